// Round 1
// baseline (607.837 us; speedup 1.0000x reference)
//
#include <hip/hip_runtime.h>

// GraphSAGE 2-layer, N=100000 nodes, IN=HID=128, OUT=64, E=1.6M edges, fp32.
// Strategy:
//   agg @ Wl == segsum((h@Wl)[src])/cnt  (scalar cnt commutes with right-matmul)
//   1) build CSR by dst (degree count -> prefix scan -> fill)
//   2) Y0 = x @ [Wl0 | Wr0]   (N x 256)
//   3) h  = relu(gather-mean(Y0[:, :128]) + bl0 + Y0[:,128:])   (wave per node)
//   4) Y1 = h @ [Wl1 | Wr1]   (N x 128), aliases Y0 buffer
//   5) out = gather-mean(Y1[:, :64]) + bl1 + Y1[:,64:]

#define LDX 132  // padded LDS row for X tile (128 + 4): keeps 16B alignment, breaks bank aliasing

__global__ __launch_bounds__(256) void k_degree(const int* __restrict__ dst,
                                                int* __restrict__ deg, int E) {
    int e = blockIdx.x * 256 + threadIdx.x;
    if (e < E) atomicAdd(&deg[dst[e]], 1);
}

__global__ __launch_bounds__(256) void k_scan1(const int* __restrict__ deg,
                                               int* __restrict__ rowptr,
                                               int* __restrict__ bsum, int N) {
    __shared__ int s[256];
    int t = threadIdx.x;
    int gid = blockIdx.x * 256 + t;
    int v = (gid < N) ? deg[gid] : 0;
    s[t] = v;
    __syncthreads();
    #pragma unroll
    for (int off = 1; off < 256; off <<= 1) {
        int x = (t >= off) ? s[t - off] : 0;
        __syncthreads();
        s[t] += x;
        __syncthreads();
    }
    if (gid < N) rowptr[gid] = s[t] - v;   // exclusive within block
    if (t == 255) bsum[blockIdx.x] = s[255];
}

__global__ __launch_bounds__(512) void k_scan2(int* __restrict__ bsum, int nb) {
    __shared__ int s[512];
    int t = threadIdx.x;
    int v = (t < nb) ? bsum[t] : 0;
    s[t] = v;
    __syncthreads();
    #pragma unroll
    for (int off = 1; off < 512; off <<= 1) {
        int x = (t >= off) ? s[t - off] : 0;
        __syncthreads();
        s[t] += x;
        __syncthreads();
    }
    if (t < nb) bsum[t] = s[t] - v;        // exclusive across blocks
}

__global__ __launch_bounds__(256) void k_scan3(int* __restrict__ rowptr,
                                               const int* __restrict__ bsum, int N) {
    int gid = blockIdx.x * 256 + threadIdx.x;
    if (gid < N) rowptr[gid] += bsum[blockIdx.x];
}

__global__ __launch_bounds__(256) void k_fill(const int* __restrict__ src,
                                              const int* __restrict__ dst,
                                              const int* __restrict__ rowptr,
                                              int* __restrict__ cursor,
                                              int* __restrict__ csr, int E) {
    int e = blockIdx.x * 256 + threadIdx.x;
    if (e < E) {
        int d = dst[e];
        int p = atomicAdd(&cursor[d], 1);
        csr[rowptr[d] + p] = src[e];
    }
}

// Y[N x NC] = X[N x 128] @ W[128 x NC], W = [WA | WB] split at `split`, both ld=ldw.
// 64x64 tile per block, 4x4 register blocking, 256 threads.
__global__ __launch_bounds__(256) void k_gemm(const float* __restrict__ X,
                                              const float* __restrict__ WA,
                                              const float* __restrict__ WB,
                                              float* __restrict__ Y,
                                              int Nrows, int split, int ldw, int NC) {
    __shared__ float Xs[64 * LDX];     // row-major [r][k], padded
    __shared__ float Ws[128 * 64];     // k-major   [k][c]
    const int t = threadIdx.x;
    const int row0 = blockIdx.x * 64;
    const int c0 = blockIdx.y * 64;
    const float* Wp; int coff;
    if (c0 < split) { Wp = WA; coff = c0; } else { Wp = WB; coff = c0 - split; }

    #pragma unroll
    for (int it = 0; it < 8; ++it) {   // stage X tile (coalesced float4)
        int idx4 = (it * 256 + t) * 4;
        int r = idx4 >> 7, k = idx4 & 127;
        int grow = row0 + r; if (grow > Nrows - 1) grow = Nrows - 1;
        float4 v = *(const float4*)(X + (size_t)grow * 128 + k);
        *(float4*)(Xs + r * LDX + k) = v;
    }
    #pragma unroll
    for (int it = 0; it < 8; ++it) {   // stage W tile (global layout == LDS layout)
        int idx4 = (it * 256 + t) * 4;
        int k = idx4 >> 6, c = idx4 & 63;
        float4 v = *(const float4*)(Wp + (size_t)k * ldw + coff + c);
        *(float4*)(Ws + k * 64 + c) = v;
    }
    __syncthreads();

    const int tx = t & 15, ty = t >> 4;
    float acc[4][4] = {};
    #pragma unroll 2
    for (int k = 0; k < 128; k += 4) {
        float4 A[4], B[4];
        #pragma unroll
        for (int i = 0; i < 4; ++i) A[i] = *(const float4*)(Xs + (ty * 4 + i) * LDX + k);
        #pragma unroll
        for (int u = 0; u < 4; ++u) B[u] = *(const float4*)(Ws + (k + u) * 64 + tx * 4);
        #pragma unroll
        for (int i = 0; i < 4; ++i) {
            const float* av = (const float*)&A[i];
            #pragma unroll
            for (int u = 0; u < 4; ++u) {
                float a = av[u];
                acc[i][0] = fmaf(a, B[u].x, acc[i][0]);
                acc[i][1] = fmaf(a, B[u].y, acc[i][1]);
                acc[i][2] = fmaf(a, B[u].z, acc[i][2]);
                acc[i][3] = fmaf(a, B[u].w, acc[i][3]);
            }
        }
    }
    #pragma unroll
    for (int i = 0; i < 4; ++i) {
        int row = row0 + ty * 4 + i;
        if (row < Nrows) {
            float4 v = make_float4(acc[i][0], acc[i][1], acc[i][2], acc[i][3]);
            *(float4*)(Y + (size_t)row * NC + c0 + tx * 4) = v;
        }
    }
}

// One wave per node: mean over neighbors of Y0[:, :128], + bl0 + Y0[:,128:], relu.
__global__ __launch_bounds__(256) void k_agg0(const float* __restrict__ Y0,
                                              const int* __restrict__ deg,
                                              const int* __restrict__ rowptr,
                                              const int* __restrict__ csr,
                                              const float* __restrict__ bl0,
                                              float* __restrict__ h, int Nn) {
    int wave = threadIdx.x >> 6, lane = threadIdx.x & 63;
    int n = blockIdx.x * 4 + wave;
    if (n >= Nn) return;
    int dg = deg[n], st = rowptr[n];
    float2 acc = make_float2(0.f, 0.f);
    int e = 0;
    for (; e + 2 <= dg; e += 2) {
        int s0 = csr[st + e], s1 = csr[st + e + 1];
        float2 v0 = *(const float2*)(Y0 + (size_t)s0 * 256 + 2 * lane);
        float2 v1 = *(const float2*)(Y0 + (size_t)s1 * 256 + 2 * lane);
        acc.x += v0.x + v1.x; acc.y += v0.y + v1.y;
    }
    if (e < dg) {
        int s0 = csr[st + e];
        float2 v0 = *(const float2*)(Y0 + (size_t)s0 * 256 + 2 * lane);
        acc.x += v0.x; acc.y += v0.y;
    }
    float inv = 1.f / fmaxf((float)dg, 1.f);
    float2 q = *(const float2*)(Y0 + (size_t)n * 256 + 128 + 2 * lane);
    float2 b = *(const float2*)(bl0 + 2 * lane);
    float o0 = fmaxf(acc.x * inv + b.x + q.x, 0.f);
    float o1 = fmaxf(acc.y * inv + b.y + q.y, 0.f);
    *(float2*)(h + (size_t)n * 128 + 2 * lane) = make_float2(o0, o1);
}

// One wave per node: mean over neighbors of Y1[:, :64], + bl1 + Y1[:,64:]. No relu.
__global__ __launch_bounds__(256) void k_agg1(const float* __restrict__ Y1,
                                              const int* __restrict__ deg,
                                              const int* __restrict__ rowptr,
                                              const int* __restrict__ csr,
                                              const float* __restrict__ bl1,
                                              float* __restrict__ out, int Nn) {
    int wave = threadIdx.x >> 6, lane = threadIdx.x & 63;
    int n = blockIdx.x * 4 + wave;
    if (n >= Nn) return;
    int dg = deg[n], st = rowptr[n];
    float acc = 0.f;
    int e = 0;
    for (; e + 2 <= dg; e += 2) {
        int s0 = csr[st + e], s1 = csr[st + e + 1];
        acc += Y1[(size_t)s0 * 128 + lane];
        acc += Y1[(size_t)s1 * 128 + lane];
    }
    if (e < dg) acc += Y1[(size_t)csr[st + e] * 128 + lane];
    float inv = 1.f / fmaxf((float)dg, 1.f);
    float q = Y1[(size_t)n * 128 + 64 + lane];
    out[(size_t)n * 64 + lane] = acc * inv + bl1[lane] + q;
}

extern "C" void kernel_launch(void* const* d_in, const int* in_sizes, int n_in,
                              void* d_out, int out_size, void* d_ws, size_t ws_size,
                              hipStream_t stream) {
    const float* x   = (const float*)d_in[0];
    const int* eidx  = (const int*)d_in[1];
    const float* Wl0 = (const float*)d_in[2];
    const float* bl0 = (const float*)d_in[3];
    const float* Wr0 = (const float*)d_in[4];
    const float* Wl1 = (const float*)d_in[5];
    const float* bl1 = (const float*)d_in[6];
    const float* Wr1 = (const float*)d_in[7];
    float* out = (float*)d_out;

    const int N = in_sizes[0] / 128;   // 100000
    const int E = in_sizes[1] / 2;     // 1600000
    const int* src = eidx;
    const int* dst = eidx + E;

    // workspace layout
    int*   deg    = (int*)d_ws;            // N
    int*   cursor = deg + N;               // N
    int*   rowptr = cursor + N;            // N
    int*   bsum   = rowptr + N;            // 512
    int*   csr    = bsum + 512;            // E
    float* Y0     = (float*)(csr + E);     // N*256  (also reused as Y1: N*128)
    float* h      = Y0 + (size_t)N * 256;  // N*128

    hipMemsetAsync(deg, 0, (size_t)2 * N * sizeof(int), stream);  // deg + cursor

    int ebl = (E + 255) / 256;
    int nb  = (N + 255) / 256;
    k_degree<<<ebl, 256, 0, stream>>>(dst, deg, E);
    k_scan1<<<nb, 256, 0, stream>>>(deg, rowptr, bsum, N);
    k_scan2<<<1, 512, 0, stream>>>(bsum, nb);
    k_scan3<<<nb, 256, 0, stream>>>(rowptr, bsum, N);
    k_fill<<<ebl, 256, 0, stream>>>(src, dst, rowptr, cursor, csr, E);

    int rbl = (N + 63) / 64;
    // layer 0: Y0 = x @ [Wl0 | Wr0]  (N x 256)
    k_gemm<<<dim3(rbl, 4), 256, 0, stream>>>(x, Wl0, Wr0, Y0, N, 128, 128, 256);
    k_agg0<<<(N + 3) / 4, 256, 0, stream>>>(Y0, deg, rowptr, csr, bl0, h, N);
    // layer 1: Y1 = h @ [Wl1 | Wr1]  (N x 128), reuse Y0 buffer
    k_gemm<<<dim3(rbl, 2), 256, 0, stream>>>(h, Wl1, Wr1, Y0, N, 64, 64, 128);
    k_agg1<<<(N + 3) / 4, 256, 0, stream>>>(Y0, deg, rowptr, csr, bl1, out, N);
}

// Round 2
// 524.157 us; speedup vs baseline: 1.1596x; 1.1596x over previous
//
#include <hip/hip_runtime.h>

// GraphSAGE 2-layer, N=100000, IN=HID=128, OUT=64, E=1.6M, fp32 in/out.
//   agg @ Wl == segsum((h@Wl)[src])/cnt  -> GEMM first, then gather-mean.
//   All intermediate tensors (Y0, h, Y1) stored bf16; GEMMs use bf16 MFMA
//   16x16x32 with fp32 accumulate; aggregation accumulates fp32.
// Pipeline:
//   CSR build (degree -> scan -> fill)
//   pack W0, W1 into MFMA B-fragment order (bf16)
//   Y0 = x @ [Wl0|Wr0]        (N x 256, bf16)   MFMA, A=fp32->bf16 on the fly
//   h  = relu(mean gather(Y0[:, :128]) + bl0 + Y0[:,128:])   (bf16, wave/node)
//   Y1 = h @ [Wl1|Wr1]        (N x 128, bf16)   MFMA, A=bf16
//   out= mean gather(Y1[:, :64]) + bl1 + Y1[:,64:]           (fp32)

typedef short short8 __attribute__((ext_vector_type(8)));
typedef float f32x4 __attribute__((ext_vector_type(4)));

static __device__ __forceinline__ unsigned short f2bf(float f) {
    union { float f; unsigned u; } c; c.f = f;
    unsigned u = c.u + 0x7fffu + ((c.u >> 16) & 1u);   // round-to-nearest-even
    return (unsigned short)(u >> 16);
}
static __device__ __forceinline__ float bf2f(unsigned short b) {
    union { unsigned u; float f; } c; c.u = ((unsigned)b) << 16;
    return c.f;
}

// ---------------- CSR build ----------------
__global__ __launch_bounds__(256) void k_degree(const int* __restrict__ dst,
                                                int* __restrict__ deg, int E) {
    int e = blockIdx.x * 256 + threadIdx.x;
    if (e < E) atomicAdd(&deg[dst[e]], 1);
}

__global__ __launch_bounds__(256) void k_scan1(const int* __restrict__ deg,
                                               int* __restrict__ rowptr,
                                               int* __restrict__ bsum, int N) {
    __shared__ int s[256];
    int t = threadIdx.x;
    int gid = blockIdx.x * 256 + t;
    int v = (gid < N) ? deg[gid] : 0;
    s[t] = v;
    __syncthreads();
    #pragma unroll
    for (int off = 1; off < 256; off <<= 1) {
        int x = (t >= off) ? s[t - off] : 0;
        __syncthreads();
        s[t] += x;
        __syncthreads();
    }
    if (gid < N) rowptr[gid] = s[t] - v;
    if (t == 255) bsum[blockIdx.x] = s[255];
}

__global__ __launch_bounds__(512) void k_scan2(int* __restrict__ bsum, int nb) {
    __shared__ int s[512];
    int t = threadIdx.x;
    int v = (t < nb) ? bsum[t] : 0;
    s[t] = v;
    __syncthreads();
    #pragma unroll
    for (int off = 1; off < 512; off <<= 1) {
        int x = (t >= off) ? s[t - off] : 0;
        __syncthreads();
        s[t] += x;
        __syncthreads();
    }
    if (t < nb) bsum[t] = s[t] - v;
}

__global__ __launch_bounds__(256) void k_scan3(int* __restrict__ rowptr,
                                               const int* __restrict__ bsum, int N) {
    int gid = blockIdx.x * 256 + threadIdx.x;
    if (gid < N) rowptr[gid] += bsum[blockIdx.x];
}

__global__ __launch_bounds__(256) void k_fill(const int* __restrict__ src,
                                              const int* __restrict__ dst,
                                              const int* __restrict__ rowptr,
                                              int* __restrict__ cursor,
                                              int* __restrict__ csr, int E) {
    int e = blockIdx.x * 256 + threadIdx.x;
    if (e < E) {
        int d = dst[e];
        int p = atomicAdd(&cursor[d], 1);
        csr[rowptr[d] + p] = src[e];
    }
}

// ---------------- weight pack into MFMA B-fragment order ----------------
// Wp index: (((tg*4 + kk)*64 + lane)*8 + j) holds bf16 of W[kk*32+quad*8+j][tg*16+(lane&15)]
// where W = [WA | WB] column-concatenated, both 128 x CA.
__global__ __launch_bounds__(256) void k_pack(const float* __restrict__ WA,
                                              const float* __restrict__ WB,
                                              int CA, int NC,
                                              unsigned short* __restrict__ Wp) {
    int tid = blockIdx.x * 256 + threadIdx.x;
    if (tid >= NC * 16) return;            // (NC/16 tiles) * 4 kk * 64 lanes
    int lane = tid & 63, kk = (tid >> 6) & 3, tg = tid >> 8;
    int l15 = lane & 15, quad = lane >> 4;
    int c = tg * 16 + l15;
    const float* W = (c < CA) ? WA : WB;
    int cc = (c < CA) ? c : c - CA;
    unsigned short o[8];
    #pragma unroll
    for (int j = 0; j < 8; ++j) {
        int k = kk * 32 + quad * 8 + j;
        o[j] = f2bf(W[(size_t)k * CA + cc]);
    }
    short8 v;
    #pragma unroll
    for (int j = 0; j < 8; ++j) v[j] = (short)o[j];
    *(short8*)(Wp + (size_t)tid * 8) = v;
}

// ---------------- MFMA GEMM: Y[N x NC] = A[N x 128] @ W ----------------
// block = 256 thr = 4 waves; block tile 32 rows; wave handles T col-tiles (16 wide).
// A loaded straight from global (rows L1-resident per block), B from packed Wp.
template<int T, bool ABF16>
__global__ __launch_bounds__(256) void k_gemm(const void* __restrict__ Xv,
                                              const unsigned short* __restrict__ Wp,
                                              unsigned short* __restrict__ Y,
                                              int Nrows, int NC) {
    const int t = threadIdx.x;
    const int wave = t >> 6, lane = t & 63;
    const int quad = lane >> 4, l15 = lane & 15;
    const int row0 = blockIdx.x * 32;
    const int c0w = wave * (T * 16);

    f32x4 acc[2][T];
    #pragma unroll
    for (int mt = 0; mt < 2; ++mt)
        #pragma unroll
        for (int tt = 0; tt < T; ++tt) acc[mt][tt] = (f32x4){0.f, 0.f, 0.f, 0.f};

    #pragma unroll
    for (int kk = 0; kk < 4; ++kk) {
        const int k0 = kk * 32 + quad * 8;
        short8 a[2];
        #pragma unroll
        for (int mt = 0; mt < 2; ++mt) {
            int row = row0 + mt * 16 + l15;
            if (row > Nrows - 1) row = Nrows - 1;
            if (ABF16) {
                a[mt] = *(const short8*)((const unsigned short*)Xv + (size_t)row * 128 + k0);
            } else {
                const float* xp = (const float*)Xv + (size_t)row * 128 + k0;
                float4 f0 = *(const float4*)xp;
                float4 f1 = *(const float4*)(xp + 4);
                short8 v;
                v[0] = (short)f2bf(f0.x); v[1] = (short)f2bf(f0.y);
                v[2] = (short)f2bf(f0.z); v[3] = (short)f2bf(f0.w);
                v[4] = (short)f2bf(f1.x); v[5] = (short)f2bf(f1.y);
                v[6] = (short)f2bf(f1.z); v[7] = (short)f2bf(f1.w);
                a[mt] = v;
            }
        }
        short8 b[T];
        #pragma unroll
        for (int tt = 0; tt < T; ++tt) {
            int tg = (c0w >> 4) + tt;
            b[tt] = *(const short8*)(Wp + ((size_t)(tg * 4 + kk) * 64 + lane) * 8);
        }
        #pragma unroll
        for (int mt = 0; mt < 2; ++mt)
            #pragma unroll
            for (int tt = 0; tt < T; ++tt)
                acc[mt][tt] = __builtin_amdgcn_mfma_f32_16x16x32_bf16(
                    a[mt], b[tt], acc[mt][tt], 0, 0, 0);
    }

    #pragma unroll
    for (int mt = 0; mt < 2; ++mt) {
        #pragma unroll
        for (int r = 0; r < 4; ++r) {
            int row = row0 + mt * 16 + quad * 4 + r;
            if (row < Nrows) {
                #pragma unroll
                for (int tt = 0; tt < T; ++tt)
                    Y[(size_t)row * NC + c0w + tt * 16 + l15] = f2bf(acc[mt][tt][r]);
            }
        }
    }
}

// ---------------- aggregation (wave per node) ----------------
// h = relu(mean gather(Y0[:, :128]) + bl0 + Y0[:,128:]); Y0 bf16 256-wide, h bf16.
__global__ __launch_bounds__(256) void k_agg0(const unsigned short* __restrict__ Y0,
                                              const int* __restrict__ deg,
                                              const int* __restrict__ rowptr,
                                              const int* __restrict__ csr,
                                              const float* __restrict__ bl0,
                                              unsigned short* __restrict__ h, int Nn) {
    int wave = threadIdx.x >> 6, lane = threadIdx.x & 63;
    int n = blockIdx.x * 4 + wave;
    if (n >= Nn) return;
    int dg = deg[n], st = rowptr[n];
    float ax = 0.f, ay = 0.f;
    int e = 0;
    for (; e + 2 <= dg; e += 2) {
        int s0 = csr[st + e], s1 = csr[st + e + 1];
        unsigned u0 = *(const unsigned*)(Y0 + (size_t)s0 * 256 + 2 * lane);
        unsigned u1 = *(const unsigned*)(Y0 + (size_t)s1 * 256 + 2 * lane);
        ax += bf2f((unsigned short)u0) + bf2f((unsigned short)u1);
        ay += bf2f((unsigned short)(u0 >> 16)) + bf2f((unsigned short)(u1 >> 16));
    }
    if (e < dg) {
        unsigned u0 = *(const unsigned*)(Y0 + (size_t)csr[st + e] * 256 + 2 * lane);
        ax += bf2f((unsigned short)u0);
        ay += bf2f((unsigned short)(u0 >> 16));
    }
    float inv = 1.f / fmaxf((float)dg, 1.f);
    unsigned ur = *(const unsigned*)(Y0 + (size_t)n * 256 + 128 + 2 * lane);
    float2 b = *(const float2*)(bl0 + 2 * lane);
    float o0 = fmaxf(ax * inv + b.x + bf2f((unsigned short)ur), 0.f);
    float o1 = fmaxf(ay * inv + b.y + bf2f((unsigned short)(ur >> 16)), 0.f);
    unsigned up = (unsigned)f2bf(o0) | ((unsigned)f2bf(o1) << 16);
    *(unsigned*)(h + (size_t)n * 128 + 2 * lane) = up;
}

// out = mean gather(Y1[:, :64]) + bl1 + Y1[:,64:]; Y1 bf16 128-wide, out fp32.
__global__ __launch_bounds__(256) void k_agg1(const unsigned short* __restrict__ Y1,
                                              const int* __restrict__ deg,
                                              const int* __restrict__ rowptr,
                                              const int* __restrict__ csr,
                                              const float* __restrict__ bl1,
                                              float* __restrict__ out, int Nn) {
    int wave = threadIdx.x >> 6, lane = threadIdx.x & 63;
    int n = blockIdx.x * 4 + wave;
    if (n >= Nn) return;
    int dg = deg[n], st = rowptr[n];
    float acc = 0.f;
    int e = 0;
    for (; e + 2 <= dg; e += 2) {
        int s0 = csr[st + e], s1 = csr[st + e + 1];
        acc += bf2f(Y1[(size_t)s0 * 128 + lane]);
        acc += bf2f(Y1[(size_t)s1 * 128 + lane]);
    }
    if (e < dg) acc += bf2f(Y1[(size_t)csr[st + e] * 128 + lane]);
    float inv = 1.f / fmaxf((float)dg, 1.f);
    float q = bf2f(Y1[(size_t)n * 128 + 64 + lane]);
    out[(size_t)n * 64 + lane] = acc * inv + bl1[lane] + q;
}

extern "C" void kernel_launch(void* const* d_in, const int* in_sizes, int n_in,
                              void* d_out, int out_size, void* d_ws, size_t ws_size,
                              hipStream_t stream) {
    const float* x   = (const float*)d_in[0];
    const int* eidx  = (const int*)d_in[1];
    const float* Wl0 = (const float*)d_in[2];
    const float* bl0 = (const float*)d_in[3];
    const float* Wr0 = (const float*)d_in[4];
    const float* Wl1 = (const float*)d_in[5];
    const float* bl1 = (const float*)d_in[6];
    const float* Wr1 = (const float*)d_in[7];
    float* out = (float*)d_out;

    const int N = in_sizes[0] / 128;   // 100000
    const int E = in_sizes[1] / 2;     // 1600000
    const int* src = eidx;
    const int* dst = eidx + E;

    // workspace layout (16B-aligned sections)
    int* deg    = (int*)d_ws;                      // N
    int* cursor = deg + N;                         // N
    int* rowptr = cursor + N;                      // N
    int* bsum   = rowptr + N;                      // 512
    int* csr    = bsum + 512;                      // E
    unsigned short* Wp0 = (unsigned short*)(csr + E);          // 256*16*8 = 32768
    unsigned short* Wp1 = Wp0 + 32768;                         // 128*16*8 = 16384
    unsigned short* Y0  = Wp1 + 16384;                         // N*256 bf16
    unsigned short* h   = Y0 + (size_t)N * 256;                // N*128 bf16
    unsigned short* Y1  = Y0;                                  // reuse Y0 (N*128)

    hipMemsetAsync(deg, 0, (size_t)2 * N * sizeof(int), stream);  // deg + cursor

    int ebl = (E + 255) / 256;
    int nb  = (N + 255) / 256;
    k_degree<<<ebl, 256, 0, stream>>>(dst, deg, E);
    k_scan1<<<nb, 256, 0, stream>>>(deg, rowptr, bsum, N);
    k_scan2<<<1, 512, 0, stream>>>(bsum, nb);
    k_scan3<<<nb, 256, 0, stream>>>(rowptr, bsum, N);
    k_fill<<<ebl, 256, 0, stream>>>(src, dst, rowptr, cursor, csr, E);

    k_pack<<<(256 * 16 + 255) / 256, 256, 0, stream>>>(Wl0, Wr0, 128, 256, Wp0);
    k_pack<<<(128 * 16 + 255) / 256, 256, 0, stream>>>(Wl1, Wr1, 64, 128, Wp1);

    int gbl = (N + 31) / 32;
    k_gemm<4, false><<<gbl, 256, 0, stream>>>((const void*)x, Wp0, Y0, N, 256);
    k_agg0<<<(N + 3) / 4, 256, 0, stream>>>(Y0, deg, rowptr, csr, bl0, h, N);
    k_gemm<2, true><<<gbl, 256, 0, stream>>>((const void*)h, Wp1, Y1, N, 128);
    k_agg1<<<(N + 3) / 4, 256, 0, stream>>>(Y1, deg, rowptr, csr, bl1, out, N);
}

// Round 3
// 365.915 us; speedup vs baseline: 1.6611x; 1.4325x over previous
//
#include <hip/hip_runtime.h>

// GraphSAGE 2-layer, N=100000, IN=HID=128, OUT=64, E=1.6M, fp32 in/out.
//   agg @ Wl == segsum((h@Wl)[src])/cnt  -> GEMM first, then gather-mean.
//   Intermediates (Y0, h, Y1) bf16; GEMMs bf16 MFMA 16x16x32, fp32 accum;
//   aggregation accumulates fp32.
// Pipeline:
//   k_degree: deg count + per-edge rank (atomic return value)
//   scan -> rowptr;  k_fill: csr[rowptr[d]+rank[e]] = src[e]  (no atomics)
//   Y0 = x @ [Wl0|Wr0]  (N x 256 bf16, MFMA)
//   h  = relu(mean-gather(Y0[:, :128]) + bl0 + Y0[:,128:])  (4 nbrs/wave)
//   Y1 = h @ [Wl1|Wr1]  (N x 128 bf16, MFMA)
//   out= mean-gather(Y1[:, :64]) + bl1 + Y1[:,64:]          (8 nbrs/wave)

typedef short short8 __attribute__((ext_vector_type(8)));
typedef float f32x4 __attribute__((ext_vector_type(4)));

static __device__ __forceinline__ unsigned short f2bf(float f) {
    union { float f; unsigned u; } c; c.f = f;
    unsigned u = c.u + 0x7fffu + ((c.u >> 16) & 1u);   // RNE
    return (unsigned short)(u >> 16);
}
static __device__ __forceinline__ float bf2f(unsigned short b) {
    union { unsigned u; float f; } c; c.u = ((unsigned)b) << 16;
    return c.f;
}
static __device__ __forceinline__ float bf2f_s(short b) {
    return bf2f((unsigned short)b);
}

// ---------------- CSR build ----------------
__global__ __launch_bounds__(256) void k_degree(const int* __restrict__ dst,
                                                int* __restrict__ deg,
                                                int* __restrict__ rank, int E) {
    int e = blockIdx.x * 256 + threadIdx.x;
    if (e < E) rank[e] = atomicAdd(&deg[dst[e]], 1);
}

__global__ __launch_bounds__(256) void k_scan1(const int* __restrict__ deg,
                                               int* __restrict__ rowptr,
                                               int* __restrict__ bsum, int N) {
    __shared__ int s[256];
    int t = threadIdx.x;
    int gid = blockIdx.x * 256 + t;
    int v = (gid < N) ? deg[gid] : 0;
    s[t] = v;
    __syncthreads();
    #pragma unroll
    for (int off = 1; off < 256; off <<= 1) {
        int x = (t >= off) ? s[t - off] : 0;
        __syncthreads();
        s[t] += x;
        __syncthreads();
    }
    if (gid < N) rowptr[gid] = s[t] - v;
    if (t == 255) bsum[blockIdx.x] = s[255];
}

__global__ __launch_bounds__(512) void k_scan2(int* __restrict__ bsum, int nb) {
    __shared__ int s[512];
    int t = threadIdx.x;
    int v = (t < nb) ? bsum[t] : 0;
    s[t] = v;
    __syncthreads();
    #pragma unroll
    for (int off = 1; off < 512; off <<= 1) {
        int x = (t >= off) ? s[t - off] : 0;
        __syncthreads();
        s[t] += x;
        __syncthreads();
    }
    if (t < nb) bsum[t] = s[t] - v;
}

__global__ __launch_bounds__(256) void k_scan3(int* __restrict__ rowptr,
                                               const int* __restrict__ bsum, int N) {
    int gid = blockIdx.x * 256 + threadIdx.x;
    if (gid < N) rowptr[gid] += bsum[blockIdx.x];
}

__global__ __launch_bounds__(256) void k_fill(const int* __restrict__ src,
                                              const int* __restrict__ dst,
                                              const int* __restrict__ rowptr,
                                              const int* __restrict__ rank,
                                              int* __restrict__ csr, int E) {
    int e = blockIdx.x * 256 + threadIdx.x;
    if (e < E) csr[rowptr[dst[e]] + rank[e]] = src[e];
}

// ---------------- weight pack into MFMA B-fragment order ----------------
__global__ __launch_bounds__(256) void k_pack(const float* __restrict__ WA,
                                              const float* __restrict__ WB,
                                              int CA, int NC,
                                              unsigned short* __restrict__ Wp) {
    int tid = blockIdx.x * 256 + threadIdx.x;
    if (tid >= NC * 16) return;
    int lane = tid & 63, kk = (tid >> 6) & 3, tg = tid >> 8;
    int l15 = lane & 15, quad = lane >> 4;
    int c = tg * 16 + l15;
    const float* W = (c < CA) ? WA : WB;
    int cc = (c < CA) ? c : c - CA;
    short8 v;
    #pragma unroll
    for (int j = 0; j < 8; ++j) {
        int k = kk * 32 + quad * 8 + j;
        v[j] = (short)f2bf(W[(size_t)k * CA + cc]);
    }
    *(short8*)(Wp + (size_t)tid * 8) = v;
}

// ---------------- MFMA GEMM: Y[N x NC] = A[N x 128] @ W ----------------
template<int T, bool ABF16>
__global__ __launch_bounds__(256) void k_gemm(const void* __restrict__ Xv,
                                              const unsigned short* __restrict__ Wp,
                                              unsigned short* __restrict__ Y,
                                              int Nrows, int NC) {
    const int t = threadIdx.x;
    const int wave = t >> 6, lane = t & 63;
    const int quad = lane >> 4, l15 = lane & 15;
    const int row0 = blockIdx.x * 32;
    const int c0w = wave * (T * 16);

    f32x4 acc[2][T];
    #pragma unroll
    for (int mt = 0; mt < 2; ++mt)
        #pragma unroll
        for (int tt = 0; tt < T; ++tt) acc[mt][tt] = (f32x4){0.f, 0.f, 0.f, 0.f};

    #pragma unroll
    for (int kk = 0; kk < 4; ++kk) {
        const int k0 = kk * 32 + quad * 8;
        short8 a[2];
        #pragma unroll
        for (int mt = 0; mt < 2; ++mt) {
            int row = row0 + mt * 16 + l15;
            if (row > Nrows - 1) row = Nrows - 1;
            if (ABF16) {
                a[mt] = *(const short8*)((const unsigned short*)Xv + (size_t)row * 128 + k0);
            } else {
                const float* xp = (const float*)Xv + (size_t)row * 128 + k0;
                float4 f0 = *(const float4*)xp;
                float4 f1 = *(const float4*)(xp + 4);
                short8 v;
                v[0] = (short)f2bf(f0.x); v[1] = (short)f2bf(f0.y);
                v[2] = (short)f2bf(f0.z); v[3] = (short)f2bf(f0.w);
                v[4] = (short)f2bf(f1.x); v[5] = (short)f2bf(f1.y);
                v[6] = (short)f2bf(f1.z); v[7] = (short)f2bf(f1.w);
                a[mt] = v;
            }
        }
        short8 b[T];
        #pragma unroll
        for (int tt = 0; tt < T; ++tt) {
            int tg = (c0w >> 4) + tt;
            b[tt] = *(const short8*)(Wp + ((size_t)(tg * 4 + kk) * 64 + lane) * 8);
        }
        #pragma unroll
        for (int mt = 0; mt < 2; ++mt)
            #pragma unroll
            for (int tt = 0; tt < T; ++tt)
                acc[mt][tt] = __builtin_amdgcn_mfma_f32_16x16x32_bf16(
                    a[mt], b[tt], acc[mt][tt], 0, 0, 0);
    }

    #pragma unroll
    for (int mt = 0; mt < 2; ++mt) {
        #pragma unroll
        for (int r = 0; r < 4; ++r) {
            int row = row0 + mt * 16 + quad * 4 + r;
            if (row < Nrows) {
                #pragma unroll
                for (int tt = 0; tt < T; ++tt)
                    Y[(size_t)row * NC + c0w + tt * 16 + l15] = f2bf(acc[mt][tt][r]);
            }
        }
    }
}

// ---------------- aggregation ----------------
// agg0: wave per node, 4 neighbors in flight (16 lanes x 16B each), 2x unroll.
__global__ __launch_bounds__(256) void k_agg0(const unsigned short* __restrict__ Y0,
                                              const int* __restrict__ deg,
                                              const int* __restrict__ rowptr,
                                              const int* __restrict__ csr,
                                              const float* __restrict__ bl0,
                                              unsigned short* __restrict__ h, int Nn) {
    int wave = threadIdx.x >> 6, lane = threadIdx.x & 63;
    int n = blockIdx.x * 4 + wave;
    if (n >= Nn) return;
    int g = lane >> 4, l15 = lane & 15;
    int dg = deg[n], st = rowptr[n];
    float acc[8] = {};
    int e = 0;
    for (; e + 8 <= dg; e += 8) {
        int s0 = csr[st + e + g];
        int s1 = csr[st + e + 4 + g];
        short8 v0 = *(const short8*)(Y0 + (size_t)s0 * 256 + l15 * 8);
        short8 v1 = *(const short8*)(Y0 + (size_t)s1 * 256 + l15 * 8);
        #pragma unroll
        for (int j = 0; j < 8; ++j) acc[j] += bf2f_s(v0[j]) + bf2f_s(v1[j]);
    }
    for (; e + 4 <= dg; e += 4) {
        int s0 = csr[st + e + g];
        short8 v0 = *(const short8*)(Y0 + (size_t)s0 * 256 + l15 * 8);
        #pragma unroll
        for (int j = 0; j < 8; ++j) acc[j] += bf2f_s(v0[j]);
    }
    if (e + g < dg) {
        int s0 = csr[st + e + g];
        short8 v0 = *(const short8*)(Y0 + (size_t)s0 * 256 + l15 * 8);
        #pragma unroll
        for (int j = 0; j < 8; ++j) acc[j] += bf2f_s(v0[j]);
    }
    // fold the 4 groups: lanes differing in bits 4,5 hold partial sums of same elems
    #pragma unroll
    for (int j = 0; j < 8; ++j) {
        acc[j] += __shfl_xor(acc[j], 16);
        acc[j] += __shfl_xor(acc[j], 32);
    }
    if (lane < 16) {   // quad 0 writes elements [l15*8, l15*8+8)
        float inv = 1.f / fmaxf((float)dg, 1.f);
        short8 rt = *(const short8*)(Y0 + (size_t)n * 256 + 128 + l15 * 8);
        float4 b0 = *(const float4*)(bl0 + l15 * 8);
        float4 b1 = *(const float4*)(bl0 + l15 * 8 + 4);
        const float* bb[2] = {(const float*)&b0, (const float*)&b1};
        short8 o;
        #pragma unroll
        for (int j = 0; j < 8; ++j) {
            float v = fmaxf(acc[j] * inv + bb[j >> 2][j & 3] + bf2f_s(rt[j]), 0.f);
            o[j] = (short)f2bf(v);
        }
        *(short8*)(h + (size_t)n * 128 + l15 * 8) = o;
    }
}

// agg1: wave per node, 8 neighbors in flight (8 lanes x 16B each), 2x unroll.
__global__ __launch_bounds__(256) void k_agg1(const unsigned short* __restrict__ Y1,
                                              const int* __restrict__ deg,
                                              const int* __restrict__ rowptr,
                                              const int* __restrict__ csr,
                                              const float* __restrict__ bl1,
                                              float* __restrict__ out, int Nn) {
    int wave = threadIdx.x >> 6, lane = threadIdx.x & 63;
    int n = blockIdx.x * 4 + wave;
    if (n >= Nn) return;
    int g = lane >> 3, l7 = lane & 7;
    int dg = deg[n], st = rowptr[n];
    float acc[8] = {};
    int e = 0;
    for (; e + 16 <= dg; e += 16) {
        int s0 = csr[st + e + g];
        int s1 = csr[st + e + 8 + g];
        short8 v0 = *(const short8*)(Y1 + (size_t)s0 * 128 + l7 * 8);
        short8 v1 = *(const short8*)(Y1 + (size_t)s1 * 128 + l7 * 8);
        #pragma unroll
        for (int j = 0; j < 8; ++j) acc[j] += bf2f_s(v0[j]) + bf2f_s(v1[j]);
    }
    for (; e + 8 <= dg; e += 8) {
        int s0 = csr[st + e + g];
        short8 v0 = *(const short8*)(Y1 + (size_t)s0 * 128 + l7 * 8);
        #pragma unroll
        for (int j = 0; j < 8; ++j) acc[j] += bf2f_s(v0[j]);
    }
    if (e + g < dg) {
        int s0 = csr[st + e + g];
        short8 v0 = *(const short8*)(Y1 + (size_t)s0 * 128 + l7 * 8);
        #pragma unroll
        for (int j = 0; j < 8; ++j) acc[j] += bf2f_s(v0[j]);
    }
    #pragma unroll
    for (int j = 0; j < 8; ++j) {
        acc[j] += __shfl_xor(acc[j], 8);
        acc[j] += __shfl_xor(acc[j], 16);
        acc[j] += __shfl_xor(acc[j], 32);
    }
    if (lane < 8) {    // elements [l7*8, l7*8+8)
        float inv = 1.f / fmaxf((float)dg, 1.f);
        short8 rt = *(const short8*)(Y1 + (size_t)n * 128 + 64 + l7 * 8);
        float4 b0 = *(const float4*)(bl1 + l7 * 8);
        float4 b1 = *(const float4*)(bl1 + l7 * 8 + 4);
        const float* bb[2] = {(const float*)&b0, (const float*)&b1};
        float4 o0, o1;
        float* oo[2] = {(float*)&o0, (float*)&o1};
        #pragma unroll
        for (int j = 0; j < 8; ++j)
            oo[j >> 2][j & 3] = acc[j] * inv + bb[j >> 2][j & 3] + bf2f_s(rt[j]);
        *(float4*)(out + (size_t)n * 64 + l7 * 8) = o0;
        *(float4*)(out + (size_t)n * 64 + l7 * 8 + 4) = o1;
    }
}

extern "C" void kernel_launch(void* const* d_in, const int* in_sizes, int n_in,
                              void* d_out, int out_size, void* d_ws, size_t ws_size,
                              hipStream_t stream) {
    const float* x   = (const float*)d_in[0];
    const int* eidx  = (const int*)d_in[1];
    const float* Wl0 = (const float*)d_in[2];
    const float* bl0 = (const float*)d_in[3];
    const float* Wr0 = (const float*)d_in[4];
    const float* Wl1 = (const float*)d_in[5];
    const float* bl1 = (const float*)d_in[6];
    const float* Wr1 = (const float*)d_in[7];
    float* out = (float*)d_out;

    const int N = in_sizes[0] / 128;   // 100000
    const int E = in_sizes[1] / 2;     // 1600000
    const int* src = eidx;
    const int* dst = eidx + E;

    // workspace layout
    int* deg    = (int*)d_ws;                      // N
    int* rowptr = deg + N;                         // N
    int* bsum   = rowptr + N;                      // 512
    int* csr    = bsum + 512;                      // E
    unsigned short* Wp0 = (unsigned short*)(csr + E);   // 256*16*8
    unsigned short* Wp1 = Wp0 + 32768;                  // 128*16*8
    unsigned short* Y0  = Wp1 + 16384;                  // N*256 bf16
    unsigned short* h   = Y0 + (size_t)N * 256;         // N*128 bf16
    unsigned short* Y1  = Y0;                           // reuse Y0
    int* rank = (int*)Y0;   // E ints; consumed by k_fill BEFORE gemm0 writes Y0

    hipMemsetAsync(deg, 0, (size_t)N * sizeof(int), stream);

    int ebl = (E + 255) / 256;
    int nb  = (N + 255) / 256;
    k_degree<<<ebl, 256, 0, stream>>>(dst, deg, rank, E);
    k_scan1<<<nb, 256, 0, stream>>>(deg, rowptr, bsum, N);
    k_scan2<<<1, 512, 0, stream>>>(bsum, nb);
    k_scan3<<<nb, 256, 0, stream>>>(rowptr, bsum, N);
    k_fill<<<ebl, 256, 0, stream>>>(src, dst, rowptr, rank, csr, E);

    k_pack<<<(256 * 16 + 255) / 256, 256, 0, stream>>>(Wl0, Wr0, 128, 256, Wp0);
    k_pack<<<(128 * 16 + 255) / 256, 256, 0, stream>>>(Wl1, Wr1, 64, 128, Wp1);

    int gbl = (N + 31) / 32;
    k_gemm<4, false><<<gbl, 256, 0, stream>>>((const void*)x, Wp0, Y0, N, 256);
    k_agg0<<<(N + 3) / 4, 256, 0, stream>>>(Y0, deg, rowptr, csr, bl0, h, N);
    k_gemm<2, true><<<gbl, 256, 0, stream>>>((const void*)h, Wp1, Y1, N, 128);
    k_agg1<<<(N + 3) / 4, 256, 0, stream>>>(Y1, deg, rowptr, csr, bl1, out, N);
}